// Round 1
// baseline (3687.764 us; speedup 1.0000x reference)
//
#include <hip/hip_runtime.h>
#include <math.h>

#define B_    2
#define N_    2048
#define DIM_  1024
#define H_    16
#define D_    64
#define INNER_ 1024
#define QKVC_ 3072

// ---------------------------------------------------------------------------
// Kernel 1: QKV GEMM  (4096 x 3072) = X(4096 x 1024) @ Wqkv(1024 x 3072)
// Epilogue scatters into head-major q/k/v workspaces: [(b*H+h)*N + n]*D + d
// ---------------------------------------------------------------------------
__global__ __launch_bounds__(256) void qkv_gemm(const float* __restrict__ X,
                                                const float* __restrict__ W,
                                                float* __restrict__ Qw,
                                                float* __restrict__ Kw,
                                                float* __restrict__ Vw) {
    __shared__ float As[16][65];
    __shared__ float Bs[16][65];
    const int tid = threadIdx.x;
    const int m0 = blockIdx.y * 64;
    const int n0 = blockIdx.x * 64;
    const int tx = tid & 15, ty = tid >> 4;
    float acc[4][4] = {};

    for (int k0 = 0; k0 < DIM_; k0 += 16) {
#pragma unroll
        for (int l = 0; l < 4; ++l) {
            int idx = tid + l * 256;
            int m = idx >> 4, kk = idx & 15;
            As[kk][m] = X[(size_t)(m0 + m) * DIM_ + k0 + kk];
            int kb = idx >> 6, nn = idx & 63;
            Bs[kb][nn] = W[(size_t)(k0 + kb) * QKVC_ + n0 + nn];
        }
        __syncthreads();
#pragma unroll
        for (int kk = 0; kk < 16; ++kk) {
            float a[4], b[4];
#pragma unroll
            for (int i = 0; i < 4; ++i) a[i] = As[kk][ty * 4 + i];
#pragma unroll
            for (int j = 0; j < 4; ++j) b[j] = Bs[kk][tx * 4 + j];
#pragma unroll
            for (int i = 0; i < 4; ++i)
#pragma unroll
                for (int j = 0; j < 4; ++j) acc[i][j] += a[i] * b[j];
        }
        __syncthreads();
    }

#pragma unroll
    for (int i = 0; i < 4; ++i) {
        int row = m0 + ty * 4 + i;
        int b = row >> 11;        // / N_
        int n = row & (N_ - 1);
#pragma unroll
        for (int j = 0; j < 4; ++j) {
            int c = n0 + tx * 4 + j;
            int seg = c >> 10;            // 0=q 1=k 2=v
            int w = c & 1023;
            int h = w >> 6, dd = w & 63;
            float* dst = (seg == 0) ? Qw : (seg == 1 ? Kw : Vw);
            dst[((size_t)(b * H_ + h) * N_ + n) * D_ + dd] = acc[i][j];
        }
    }
}

// ---------------------------------------------------------------------------
// Kernel 2: RoPE in-place on Q and K (interleaved pairs, theta=10000)
// layout: [(bh)*N + n]*D + 2*d2  (angle depends on n, d2 only)
// ---------------------------------------------------------------------------
__global__ void rope_kernel(float* __restrict__ Qw, float* __restrict__ Kw) {
    const int total = B_ * H_ * N_ * (D_ / 2);
    for (int p = blockIdx.x * blockDim.x + threadIdx.x; p < total;
         p += gridDim.x * blockDim.x) {
        int d2 = p & 31;
        int rest = p >> 5;            // bh*N + n
        int n = rest & (N_ - 1);
        size_t off = (size_t)rest * D_ + 2 * d2;
        float freq = powf(10000.0f, -(float)d2 * (1.0f / 32.0f));
        float ang = (float)n * freq;
        float s, c;
        sincosf(ang, &s, &c);
        float q0 = Qw[off], q1 = Qw[off + 1];
        Qw[off]     = q0 * c - q1 * s;
        Qw[off + 1] = q1 * c + q0 * s;
        float k0 = Kw[off], k1 = Kw[off + 1];
        Kw[off]     = k0 * c - k1 * s;
        Kw[off + 1] = k1 * c + k0 * s;
    }
}

// ---------------------------------------------------------------------------
// Kernel 3: flash-style attention, fp32.
// Block = 256 threads handles one (bh, 64-row Q tile).
// Thread (r = tid>>2, cq = tid&3): owns S/P cols [cq*16, cq*16+16) and
// O dims [cq*16, cq*16+16) of row r. Row reductions via 4-lane shfl_xor.
// Output written as (b, n, h*64+d) for the projection GEMM.
// ---------------------------------------------------------------------------
__global__ __launch_bounds__(256) void attn_kernel(const float* __restrict__ Qw,
                                                   const float* __restrict__ Kw,
                                                   const float* __restrict__ Vw,
                                                   float* __restrict__ Ow) {
    __shared__ float Qt[64][65];
    __shared__ float Kt[64][65];
    __shared__ float Vt[64][65];
    const int tid = threadIdx.x;
    const int bh = blockIdx.y;            // b*H + h
    const int q0 = blockIdx.x * 64;
    const size_t base = (size_t)bh * N_ * D_;

#pragma unroll
    for (int l = 0; l < 16; ++l) {
        int idx = tid + l * 256;
        Qt[idx >> 6][idx & 63] = Qw[base + (size_t)q0 * D_ + idx];
    }

    const int r = tid >> 2, cq = tid & 3;
    const int lane = tid & 63;
    const int lbase = lane & ~3;

    float o[16];
#pragma unroll
    for (int i = 0; i < 16; ++i) o[i] = 0.f;
    float mrow = -1e30f, lsum = 0.f;

    for (int k0 = 0; k0 < N_; k0 += 64) {
        __syncthreads();
#pragma unroll
        for (int l = 0; l < 16; ++l) {
            int idx = tid + l * 256;
            Kt[idx >> 6][idx & 63] = Kw[base + (size_t)k0 * D_ + idx];
            Vt[idx >> 6][idx & 63] = Vw[base + (size_t)k0 * D_ + idx];
        }
        __syncthreads();

        float s[16];
#pragma unroll
        for (int j = 0; j < 16; ++j) s[j] = 0.f;
#pragma unroll
        for (int d = 0; d < 64; ++d) {
            float qv = Qt[r][d];
#pragma unroll
            for (int j = 0; j < 16; ++j) s[j] += qv * Kt[cq * 16 + j][d];
        }

        float tm = -1e30f;
#pragma unroll
        for (int j = 0; j < 16; ++j) {
            s[j] *= 0.125f;                      // 1/sqrt(64)
            tm = fmaxf(tm, s[j]);
        }
        tm = fmaxf(tm, __shfl_xor(tm, 1));
        tm = fmaxf(tm, __shfl_xor(tm, 2));
        float newm = fmaxf(mrow, tm);
        float alpha = expf(mrow - newm);

        float p[16];
        float ps = 0.f;
#pragma unroll
        for (int j = 0; j < 16; ++j) {
            p[j] = expf(s[j] - newm);
            ps += p[j];
        }
        ps += __shfl_xor(ps, 1);
        ps += __shfl_xor(ps, 2);
        lsum = alpha * lsum + ps;
        mrow = newm;

#pragma unroll
        for (int i = 0; i < 16; ++i) o[i] *= alpha;

#pragma unroll
        for (int src = 0; src < 4; ++src) {
#pragma unroll
            for (int j = 0; j < 16; ++j) {
                float pv = __shfl(p[j], lbase + src);
                int c = src * 16 + j;
#pragma unroll
                for (int i = 0; i < 16; ++i) o[i] += pv * Vt[c][cq * 16 + i];
            }
        }
    }

    float inv = 1.0f / lsum;
    int b = bh >> 4, h = bh & 15;
    size_t orow = ((size_t)b * N_ + q0 + r) * INNER_ + h * 64 + cq * 16;
#pragma unroll
    for (int i = 0; i < 16; ++i) Ow[orow + i] = o[i] * inv;
}

// ---------------------------------------------------------------------------
// Kernel 4: output projection  (4096 x 1024) = O(4096 x 1024) @ Wout + bias
// ---------------------------------------------------------------------------
__global__ __launch_bounds__(256) void out_gemm(const float* __restrict__ A,
                                                const float* __restrict__ W,
                                                const float* __restrict__ bias,
                                                float* __restrict__ C) {
    __shared__ float As[16][65];
    __shared__ float Bs[16][65];
    const int tid = threadIdx.x;
    const int m0 = blockIdx.y * 64;
    const int n0 = blockIdx.x * 64;
    const int tx = tid & 15, ty = tid >> 4;
    float acc[4][4] = {};

    for (int k0 = 0; k0 < INNER_; k0 += 16) {
#pragma unroll
        for (int l = 0; l < 4; ++l) {
            int idx = tid + l * 256;
            int m = idx >> 4, kk = idx & 15;
            As[kk][m] = A[(size_t)(m0 + m) * INNER_ + k0 + kk];
            int kb = idx >> 6, nn = idx & 63;
            Bs[kb][nn] = W[(size_t)(k0 + kb) * DIM_ + n0 + nn];
        }
        __syncthreads();
#pragma unroll
        for (int kk = 0; kk < 16; ++kk) {
            float a[4], b[4];
#pragma unroll
            for (int i = 0; i < 4; ++i) a[i] = As[kk][ty * 4 + i];
#pragma unroll
            for (int j = 0; j < 4; ++j) b[j] = Bs[kk][tx * 4 + j];
#pragma unroll
            for (int i = 0; i < 4; ++i)
#pragma unroll
                for (int j = 0; j < 4; ++j) acc[i][j] += a[i] * b[j];
        }
        __syncthreads();
    }

#pragma unroll
    for (int i = 0; i < 4; ++i) {
        int row = m0 + ty * 4 + i;
#pragma unroll
        for (int j = 0; j < 4; ++j) {
            int c = n0 + tx * 4 + j;
            C[(size_t)row * DIM_ + c] = acc[i][j] + bias[c];
        }
    }
}

// ---------------------------------------------------------------------------
extern "C" void kernel_launch(void* const* d_in, const int* in_sizes, int n_in,
                              void* d_out, int out_size, void* d_ws, size_t ws_size,
                              hipStream_t stream) {
    const float* x     = (const float*)d_in[0];
    const float* w_qkv = (const float*)d_in[1];
    const float* w_out = (const float*)d_in[2];
    const float* b_out = (const float*)d_in[3];
    float* out = (float*)d_out;

    const size_t per = (size_t)B_ * H_ * N_ * D_;   // 4,194,304 floats
    float* Qw = (float*)d_ws;
    float* Kw = Qw + per;
    float* Vw = Kw + per;
    float* Ow = Vw + per;

    qkv_gemm<<<dim3(QKVC_ / 64, (B_ * N_) / 64), 256, 0, stream>>>(x, w_qkv, Qw, Kw, Vw);
    rope_kernel<<<dim3(2048), 256, 0, stream>>>(Qw, Kw);
    attn_kernel<<<dim3(N_ / 64, B_ * H_), 256, 0, stream>>>(Qw, Kw, Vw, Ow);
    out_gemm<<<dim3(DIM_ / 64, (B_ * N_) / 64), 256, 0, stream>>>(Ow, w_out, b_out, out);
}

// Round 2
// 836.767 us; speedup vs baseline: 4.4072x; 4.4072x over previous
//
#include <hip/hip_runtime.h>
#include <math.h>

#define B_    2
#define N_    2048
#define DIM_  1024
#define H_    16
#define D_    64
#define INNER_ 1024
#define QKVC_ 3072

typedef __attribute__((ext_vector_type(8))) short short8;
typedef __attribute__((ext_vector_type(4))) float f32x4;

static __device__ __forceinline__ unsigned short f2bf(float f) {
    unsigned int u = __float_as_uint(f);
    u = (u + 0x7fff + ((u >> 16) & 1)) >> 16;   // round-nearest-even
    return (unsigned short)u;
}
static __device__ __forceinline__ float bf2f(unsigned short b) {
    return __uint_as_float(((unsigned int)b) << 16);
}

// ---------------------------------------------------------------------------
// Kernel 1: QKV GEMM  (4096 x 3072) = X(4096 x 1024) @ Wqkv(1024 x 3072), fp32
// Epilogue scatters bf16 into head-major q/k/v: [(b*H+h)*N + n]*D + d
// ---------------------------------------------------------------------------
__global__ __launch_bounds__(256) void qkv_gemm(const float* __restrict__ X,
                                                const float* __restrict__ W,
                                                unsigned short* __restrict__ Qb,
                                                unsigned short* __restrict__ Kb,
                                                unsigned short* __restrict__ Vb) {
    __shared__ float As[16][65];
    __shared__ float Bs[16][65];
    const int tid = threadIdx.x;
    const int m0 = blockIdx.y * 64;
    const int n0 = blockIdx.x * 64;
    const int tx = tid & 15, ty = tid >> 4;
    float acc[4][4] = {};

    for (int k0 = 0; k0 < DIM_; k0 += 16) {
#pragma unroll
        for (int l = 0; l < 4; ++l) {
            int idx = tid + l * 256;
            int m = idx >> 4, kk = idx & 15;
            As[kk][m] = X[(size_t)(m0 + m) * DIM_ + k0 + kk];
            int kb = idx >> 6, nn = idx & 63;
            Bs[kb][nn] = W[(size_t)(k0 + kb) * QKVC_ + n0 + nn];
        }
        __syncthreads();
#pragma unroll
        for (int kk = 0; kk < 16; ++kk) {
            float a[4], b[4];
#pragma unroll
            for (int i = 0; i < 4; ++i) a[i] = As[kk][ty * 4 + i];
#pragma unroll
            for (int j = 0; j < 4; ++j) b[j] = Bs[kk][tx * 4 + j];
#pragma unroll
            for (int i = 0; i < 4; ++i)
#pragma unroll
                for (int j = 0; j < 4; ++j) acc[i][j] += a[i] * b[j];
        }
        __syncthreads();
    }

#pragma unroll
    for (int i = 0; i < 4; ++i) {
        int row = m0 + ty * 4 + i;
        int b = row >> 11;
        int n = row & (N_ - 1);
#pragma unroll
        for (int j = 0; j < 4; ++j) {
            int c = n0 + tx * 4 + j;
            int seg = c >> 10;            // 0=q 1=k 2=v
            int w = c & 1023;
            int h = w >> 6, dd = w & 63;
            unsigned short* dst = (seg == 0) ? Qb : (seg == 1 ? Kb : Vb);
            dst[((size_t)(b * H_ + h) * N_ + n) * D_ + dd] = f2bf(acc[i][j]);
        }
    }
}

// ---------------------------------------------------------------------------
// Kernel 2: RoPE in-place on bf16 Q and K (interleaved pairs, theta=10000)
// ---------------------------------------------------------------------------
__global__ void rope_kernel(unsigned short* __restrict__ Qb,
                            unsigned short* __restrict__ Kb) {
    const int total = B_ * H_ * N_ * (D_ / 2);
    for (int p = blockIdx.x * blockDim.x + threadIdx.x; p < total;
         p += gridDim.x * blockDim.x) {
        int d2 = p & 31;
        int rest = p >> 5;            // bh*N + n
        int n = rest & (N_ - 1);
        size_t off = (size_t)rest * D_ + 2 * d2;
        float freq = powf(10000.0f, -(float)d2 * (1.0f / 32.0f));
        float ang = (float)n * freq;
        float s, c;
        sincosf(ang, &s, &c);

        unsigned int uq = *(unsigned int*)(Qb + off);
        float q0 = __uint_as_float(uq << 16);
        float q1 = __uint_as_float(uq & 0xffff0000u);
        unsigned int rq = (unsigned int)f2bf(q0 * c - q1 * s) |
                          ((unsigned int)f2bf(q1 * c + q0 * s) << 16);
        *(unsigned int*)(Qb + off) = rq;

        unsigned int uk = *(unsigned int*)(Kb + off);
        float k0 = __uint_as_float(uk << 16);
        float k1 = __uint_as_float(uk & 0xffff0000u);
        unsigned int rk = (unsigned int)f2bf(k0 * c - k1 * s) |
                          ((unsigned int)f2bf(k1 * c + k0 * s) << 16);
        *(unsigned int*)(Kb + off) = rk;
    }
}

// ---------------------------------------------------------------------------
// Kernel 3: flash attention on bf16 MFMA 16x16x32, fp32 softmax/accum.
// Block = 256 threads (4 waves), 64 q-rows; wave w owns rows w*16..w*16+15.
// A-frag (16x32): lane holds row l&15, k=(l>>4)*8+j  (8 contiguous, 16B)
// B-frag (32x16): lane holds col l&15, k=(l>>4)*8+j
// C/D:            lane holds col l&15, row=(l>>4)*4+reg           [m89]
// S = Q·K^T  (A=Q rows from global, B=K rows from global — both contiguous)
// P transposed via per-wave padded LDS; V staged transposed in LDS.
// ---------------------------------------------------------------------------
#define PADV 72
__global__ __launch_bounds__(256) void attn_mfma(const unsigned short* __restrict__ Qb,
                                                 const unsigned short* __restrict__ Kb,
                                                 const unsigned short* __restrict__ Vb,
                                                 float* __restrict__ Ow) {
    __shared__ __align__(16) unsigned short Vt[64][PADV];      // V^T: [d][kv]
    __shared__ __align__(16) unsigned short Pl[4][16][PADV];   // per-wave P: [q][kv]
    const int tid = threadIdx.x;
    const int w = tid >> 6;
    const int l = tid & 63;
    const int lr = l & 15, lg = l >> 4;
    const int bh = blockIdx.y;
    const int q0 = blockIdx.x * 64;
    const size_t base = (size_t)bh * N_ * D_;

    // Q fragments (persistent): rows q0 + w*16 + lr
    const unsigned short* qrow = Qb + base + (size_t)(q0 + w * 16 + lr) * D_ + lg * 8;
    short8 qf0 = *(const short8*)qrow;
    short8 qf1 = *(const short8*)(qrow + 32);

    f32x4 oacc[4] = {};          // [dt] d-subtiles
    float m[4], lsum[4];
#pragma unroll
    for (int r = 0; r < 4; ++r) { m[r] = -1e30f; lsum[r] = 0.f; }

    for (int k0 = 0; k0 < N_; k0 += 64) {
        __syncthreads();         // prev PV reads of Vt done
        // ---- stage V transposed: thread (kv=tid&63, d0=(tid>>6)*16) ----
        {
            int kv = tid & 63, d0 = (tid >> 6) * 16;
            const unsigned short* src = Vb + base + (size_t)(k0 + kv) * D_ + d0;
            short8 v0 = *(const short8*)src;
            short8 v1 = *(const short8*)(src + 8);
#pragma unroll
            for (int j = 0; j < 8; ++j) {
                Vt[d0 + j][kv]     = (unsigned short)v0[j];
                Vt[d0 + 8 + j][kv] = (unsigned short)v1[j];
            }
        }
        // ---- S = Q·K^T : 8 mfma, K frags straight from global/L2 ----
        f32x4 sacc[4] = {};
#pragma unroll
        for (int t = 0; t < 4; ++t) {
            const unsigned short* krow = Kb + base + (size_t)(k0 + t * 16 + lr) * D_ + lg * 8;
            short8 kf0 = *(const short8*)krow;
            short8 kf1 = *(const short8*)(krow + 32);
            sacc[t] = __builtin_amdgcn_mfma_f32_16x16x32_bf16(qf0, kf0, sacc[t], 0, 0, 0);
            sacc[t] = __builtin_amdgcn_mfma_f32_16x16x32_bf16(qf1, kf1, sacc[t], 0, 0, 0);
        }
        __syncthreads();         // Vt ready

        // ---- online softmax; lane holds rows q=lg*4+r, cols kv=lr+16t ----
        float tm[4];
#pragma unroll
        for (int r = 0; r < 4; ++r) tm[r] = -1e30f;
#pragma unroll
        for (int t = 0; t < 4; ++t)
#pragma unroll
            for (int r = 0; r < 4; ++r) {
                float s = sacc[t][r] * 0.125f;
                sacc[t][r] = s;
                tm[r] = fmaxf(tm[r], s);
            }
#pragma unroll
        for (int mask = 1; mask <= 8; mask <<= 1)
#pragma unroll
            for (int r = 0; r < 4; ++r) tm[r] = fmaxf(tm[r], __shfl_xor(tm[r], mask));

        float al[4], ps[4];
#pragma unroll
        for (int r = 0; r < 4; ++r) {
            float nm = fmaxf(m[r], tm[r]);
            al[r] = __expf(m[r] - nm);
            m[r] = nm;
            ps[r] = 0.f;
        }
#pragma unroll
        for (int t = 0; t < 4; ++t)
#pragma unroll
            for (int r = 0; r < 4; ++r) {
                float e = __expf(sacc[t][r] - m[r]);
                ps[r] += e;
                Pl[w][lg * 4 + r][lr + 16 * t] = f2bf(e);
            }
#pragma unroll
        for (int mask = 1; mask <= 8; mask <<= 1)
#pragma unroll
            for (int r = 0; r < 4; ++r) ps[r] += __shfl_xor(ps[r], mask);
#pragma unroll
        for (int r = 0; r < 4; ++r) lsum[r] = lsum[r] * al[r] + ps[r];
#pragma unroll
        for (int dt = 0; dt < 4; ++dt)
#pragma unroll
            for (int r = 0; r < 4; ++r) oacc[dt][r] *= al[r];

        // ---- PV: A = P (from own-wave LDS), B = V^T rows (contiguous kv) ----
#pragma unroll
        for (int h = 0; h < 2; ++h) {
            short8 pf = *(const short8*)&Pl[w][lr][lg * 8 + 32 * h];
#pragma unroll
            for (int dt = 0; dt < 4; ++dt) {
                short8 vf = *(const short8*)&Vt[dt * 16 + lr][lg * 8 + 32 * h];
                oacc[dt] = __builtin_amdgcn_mfma_f32_16x16x32_bf16(pf, vf, oacc[dt], 0, 0, 0);
            }
        }
    }

    // ---- epilogue: O[q= q0+w*16+lg*4+r][d=lr+16dt] / lsum ----
    int b = bh >> 4, h = bh & 15;
#pragma unroll
    for (int r = 0; r < 4; ++r) {
        float inv = 1.0f / lsum[r];
        size_t orow = ((size_t)b * N_ + q0 + w * 16 + lg * 4 + r) * INNER_ + h * 64 + lr;
#pragma unroll
        for (int dt = 0; dt < 4; ++dt) Ow[orow + 16 * dt] = oacc[dt][r] * inv;
    }
}

// ---------------------------------------------------------------------------
// Kernel 4: output projection  (4096 x 1024) = O @ Wout + bias, fp32
// ---------------------------------------------------------------------------
__global__ __launch_bounds__(256) void out_gemm(const float* __restrict__ A,
                                                const float* __restrict__ W,
                                                const float* __restrict__ bias,
                                                float* __restrict__ C) {
    __shared__ float As[16][65];
    __shared__ float Bs[16][65];
    const int tid = threadIdx.x;
    const int m0 = blockIdx.y * 64;
    const int n0 = blockIdx.x * 64;
    const int tx = tid & 15, ty = tid >> 4;
    float acc[4][4] = {};

    for (int k0 = 0; k0 < INNER_; k0 += 16) {
#pragma unroll
        for (int l = 0; l < 4; ++l) {
            int idx = tid + l * 256;
            int m = idx >> 4, kk = idx & 15;
            As[kk][m] = A[(size_t)(m0 + m) * INNER_ + k0 + kk];
            int kb = idx >> 6, nn = idx & 63;
            Bs[kb][nn] = W[(size_t)(k0 + kb) * DIM_ + n0 + nn];
        }
        __syncthreads();
#pragma unroll
        for (int kk = 0; kk < 16; ++kk) {
            float a[4], b[4];
#pragma unroll
            for (int i = 0; i < 4; ++i) a[i] = As[kk][ty * 4 + i];
#pragma unroll
            for (int j = 0; j < 4; ++j) b[j] = Bs[kk][tx * 4 + j];
#pragma unroll
            for (int i = 0; i < 4; ++i)
#pragma unroll
                for (int j = 0; j < 4; ++j) acc[i][j] += a[i] * b[j];
        }
        __syncthreads();
    }

#pragma unroll
    for (int i = 0; i < 4; ++i) {
        int row = m0 + ty * 4 + i;
#pragma unroll
        for (int j = 0; j < 4; ++j) {
            int c = n0 + tx * 4 + j;
            C[(size_t)row * DIM_ + c] = acc[i][j] + bias[c];
        }
    }
}

// ---------------------------------------------------------------------------
extern "C" void kernel_launch(void* const* d_in, const int* in_sizes, int n_in,
                              void* d_out, int out_size, void* d_ws, size_t ws_size,
                              hipStream_t stream) {
    const float* x     = (const float*)d_in[0];
    const float* w_qkv = (const float*)d_in[1];
    const float* w_out = (const float*)d_in[2];
    const float* b_out = (const float*)d_in[3];
    float* out = (float*)d_out;

    const size_t per = (size_t)B_ * H_ * N_ * D_;   // 4,194,304 elements
    unsigned short* Qb = (unsigned short*)d_ws;
    unsigned short* Kb = Qb + per;
    unsigned short* Vb = Kb + per;
    float* Ow = (float*)(Vb + per);

    qkv_gemm<<<dim3(QKVC_ / 64, (B_ * N_) / 64), 256, 0, stream>>>(x, w_qkv, Qb, Kb, Vb);
    rope_kernel<<<dim3(2048), 256, 0, stream>>>(Qb, Kb);
    attn_mfma<<<dim3(N_ / 64, B_ * H_), 256, 0, stream>>>(Qb, Kb, Vb, Ow);
    out_gemm<<<dim3(DIM_ / 64, (B_ * N_) / 64), 256, 0, stream>>>(Ow, w_out, b_out, out);
}

// Round 3
// 341.007 us; speedup vs baseline: 10.8143x; 2.4538x over previous
//
#include <hip/hip_runtime.h>
#include <math.h>

#define B_    2
#define N_    2048
#define DIM_  1024
#define H_    16
#define D_    64
#define INNER_ 1024
#define QKVC_ 3072

typedef __attribute__((ext_vector_type(8))) short short8;
typedef __attribute__((ext_vector_type(4))) float f32x4;
typedef __attribute__((ext_vector_type(4))) float float4v;

static __device__ __forceinline__ unsigned short f2bf(float f) {
    unsigned int u = __float_as_uint(f);
    u = (u + 0x7fff + ((u >> 16) & 1)) >> 16;   // RNE
    return (unsigned short)u;
}
static __device__ __forceinline__ float bf2f(unsigned short b) {
    return __uint_as_float(((unsigned int)b) << 16);
}

static __device__ __forceinline__ void gload16(const void* g, void* l) {
    __builtin_amdgcn_global_load_lds((__attribute__((address_space(1))) void*)(g),
                                     (__attribute__((address_space(3))) void*)(l),
                                     16, 0, 0);
}

// ---------------------------------------------------------------------------
// convert_x: fp32 (rows x 1024) -> bf16 hi/lo, same layout. 8 elems/thread.
// ---------------------------------------------------------------------------
__global__ __launch_bounds__(256) void convert_x(const float* __restrict__ X,
                                                 unsigned short* __restrict__ Xhi,
                                                 unsigned short* __restrict__ Xlo) {
    int t = blockIdx.x * blockDim.x + threadIdx.x;   // 4M/8 threads
    size_t off = (size_t)t * 8;
    float4v a = *(const float4v*)(X + off);
    float4v b = *(const float4v*)(X + off + 4);
    short8 hi, lo;
#pragma unroll
    for (int j = 0; j < 4; ++j) {
        unsigned short h = f2bf(a[j]); hi[j] = (short)h; lo[j] = (short)f2bf(a[j] - bf2f(h));
        unsigned short h2 = f2bf(b[j]); hi[4 + j] = (short)h2; lo[4 + j] = (short)f2bf(b[j] - bf2f(h2));
    }
    *(short8*)(Xhi + off) = hi;
    *(short8*)(Xlo + off) = lo;
}

// ---------------------------------------------------------------------------
// convert_w_T: W fp32 (K=1024 x Nw) -> W^T bf16 hi/lo (Nw x 1024).
// 64x64 tiles via padded LDS.
// ---------------------------------------------------------------------------
__global__ __launch_bounds__(256) void convert_w_T(const float* __restrict__ W,
                                                   unsigned short* __restrict__ Thi,
                                                   unsigned short* __restrict__ Tlo,
                                                   int Nw) {
    __shared__ unsigned short Shi[64][65];
    __shared__ unsigned short Slo[64][65];
    const int tid = threadIdx.x;
    const int n0 = blockIdx.x * 64;
    const int k0 = blockIdx.y * 64;
#pragma unroll
    for (int l = 0; l < 16; ++l) {
        int idx = tid + l * 256;
        int r = idx >> 6, c = idx & 63;            // k-row r, n-col c
        float v = W[(size_t)(k0 + r) * Nw + n0 + c];
        unsigned short h = f2bf(v);
        Shi[c][r] = h;
        Slo[c][r] = f2bf(v - bf2f(h));
    }
    __syncthreads();
#pragma unroll
    for (int l = 0; l < 16; ++l) {
        int idx = tid + l * 256;
        int r = idx >> 6, c = idx & 63;            // n-row r, k-col c
        size_t o = (size_t)(n0 + r) * 1024 + k0 + c;
        Thi[o] = Shi[r][c];
        Tlo[o] = Slo[r][c];
    }
}

// ---------------------------------------------------------------------------
// Split-bf16 GEMM core: C(M x N) = A(M x 1024) * B^T(N x 1024), fp32 acc.
// 128x128 tile, BK=32, 4 waves (2x2), 48 MFMA / K-step.
// A,B staged hi+lo via global_load_lds (linear [128][32] LDS).
// ---------------------------------------------------------------------------
#define GEMM_STAGE(gA_hi, gA_lo, gB_hi, gB_lo)                                     \
    {                                                                              \
        int c0 = w * 2, c1 = w * 2 + 1;                                            \
        int ra0 = c0 * 16 + (lane >> 2), ra1 = c1 * 16 + (lane >> 2);              \
        int kc = (lane & 3) * 8;                                                   \
        gload16(gA_hi + (size_t)(m0 + ra0) * 1024 + k0 + kc, sAhi + c0 * 512);     \
        gload16(gA_hi + (size_t)(m0 + ra1) * 1024 + k0 + kc, sAhi + c1 * 512);     \
        gload16(gA_lo + (size_t)(m0 + ra0) * 1024 + k0 + kc, sAlo + c0 * 512);     \
        gload16(gA_lo + (size_t)(m0 + ra1) * 1024 + k0 + kc, sAlo + c1 * 512);     \
        gload16(gB_hi + (size_t)(n0 + ra0) * 1024 + k0 + kc, sBhi + c0 * 512);     \
        gload16(gB_hi + (size_t)(n0 + ra1) * 1024 + k0 + kc, sBhi + c1 * 512);     \
        gload16(gB_lo + (size_t)(n0 + ra0) * 1024 + k0 + kc, sBlo + c0 * 512);     \
        gload16(gB_lo + (size_t)(n0 + ra1) * 1024 + k0 + kc, sBlo + c1 * 512);     \
    }

#define GEMM_BODY()                                                                \
    short8 ah[4], al[4], bh[4], bl[4];                                             \
    _Pragma("unroll") for (int f = 0; f < 4; ++f) {                                \
        int offa = (wr + f * 16 + (lane & 15)) * 32 + (lane >> 4) * 8;             \
        ah[f] = *(const short8*)&sAhi[offa];                                       \
        al[f] = *(const short8*)&sAlo[offa];                                       \
        int offb = (wc + f * 16 + (lane & 15)) * 32 + (lane >> 4) * 8;             \
        bh[f] = *(const short8*)&sBhi[offb];                                       \
        bl[f] = *(const short8*)&sBlo[offb];                                       \
    }                                                                              \
    _Pragma("unroll") for (int i = 0; i < 4; ++i)                                  \
        _Pragma("unroll") for (int j = 0; j < 4; ++j) {                            \
            acc[i][j] = __builtin_amdgcn_mfma_f32_16x16x32_bf16(ah[i], bh[j], acc[i][j], 0, 0, 0); \
            acc[i][j] = __builtin_amdgcn_mfma_f32_16x16x32_bf16(al[i], bh[j], acc[i][j], 0, 0, 0); \
            acc[i][j] = __builtin_amdgcn_mfma_f32_16x16x32_bf16(ah[i], bl[j], acc[i][j], 0, 0, 0); \
        }

__global__ __launch_bounds__(256) void qkv_gemm_mfma(const unsigned short* __restrict__ Ahi,
                                                     const unsigned short* __restrict__ Alo,
                                                     const unsigned short* __restrict__ Bhi,
                                                     const unsigned short* __restrict__ Blo,
                                                     unsigned short* __restrict__ Qb,
                                                     unsigned short* __restrict__ Kb,
                                                     unsigned short* __restrict__ Vb) {
    __shared__ __align__(16) unsigned short sAhi[4096], sAlo[4096], sBhi[4096], sBlo[4096];
    const int tid = threadIdx.x;
    const int lane = tid & 63, w = tid >> 6;
    const int wr = (w >> 1) * 64, wc = (w & 1) * 64;
    const int m0 = blockIdx.y * 128, n0 = blockIdx.x * 128;
    f32x4 acc[4][4] = {};

    for (int k0 = 0; k0 < 1024; k0 += 32) {
        GEMM_STAGE(Ahi, Alo, Bhi, Blo);
        __syncthreads();
        GEMM_BODY();
        __syncthreads();
    }

#pragma unroll
    for (int i = 0; i < 4; ++i) {
        int mbase = m0 + wr + i * 16 + (lane >> 4) * 4;
#pragma unroll
        for (int j = 0; j < 4; ++j) {
            int col = n0 + wc + j * 16 + (lane & 15);
            int seg = col >> 10;
            int wcol = col & 1023;
            int h = wcol >> 6, dd = wcol & 63;
            unsigned short* dst = (seg == 0) ? Qb : (seg == 1 ? Kb : Vb);
#pragma unroll
            for (int r = 0; r < 4; ++r) {
                int row = mbase + r;
                int b = row >> 11, n = row & (N_ - 1);
                dst[((size_t)(b * H_ + h) * N_ + n) * D_ + dd] = f2bf(acc[i][j][r]);
            }
        }
    }
}

__global__ __launch_bounds__(256) void out_gemm_mfma(const unsigned short* __restrict__ Ahi,
                                                     const unsigned short* __restrict__ Alo,
                                                     const unsigned short* __restrict__ Bhi,
                                                     const unsigned short* __restrict__ Blo,
                                                     const float* __restrict__ bias,
                                                     float* __restrict__ C) {
    __shared__ __align__(16) unsigned short sAhi[4096], sAlo[4096], sBhi[4096], sBlo[4096];
    const int tid = threadIdx.x;
    const int lane = tid & 63, w = tid >> 6;
    const int wr = (w >> 1) * 64, wc = (w & 1) * 64;
    const int m0 = blockIdx.y * 128, n0 = blockIdx.x * 128;
    f32x4 acc[4][4] = {};

    for (int k0 = 0; k0 < 1024; k0 += 32) {
        GEMM_STAGE(Ahi, Alo, Bhi, Blo);
        __syncthreads();
        GEMM_BODY();
        __syncthreads();
    }

#pragma unroll
    for (int i = 0; i < 4; ++i) {
        int mbase = m0 + wr + i * 16 + (lane >> 4) * 4;
#pragma unroll
        for (int j = 0; j < 4; ++j) {
            int col = n0 + wc + j * 16 + (lane & 15);
            float bv = bias[col];
#pragma unroll
            for (int r = 0; r < 4; ++r)
                C[(size_t)(mbase + r) * DIM_ + col] = acc[i][j][r] + bv;
        }
    }
}

// ---------------------------------------------------------------------------
// RoPE in-place on bf16 Q and K (interleaved pairs, theta=10000)
// ---------------------------------------------------------------------------
__global__ void rope_kernel(unsigned short* __restrict__ Qb,
                            unsigned short* __restrict__ Kb) {
    const int total = B_ * H_ * N_ * (D_ / 2);
    for (int p = blockIdx.x * blockDim.x + threadIdx.x; p < total;
         p += gridDim.x * blockDim.x) {
        int d2 = p & 31;
        int rest = p >> 5;
        int n = rest & (N_ - 1);
        size_t off = (size_t)rest * D_ + 2 * d2;
        float freq = powf(10000.0f, -(float)d2 * (1.0f / 32.0f));
        float ang = (float)n * freq;
        float s, c;
        sincosf(ang, &s, &c);

        unsigned int uq = *(unsigned int*)(Qb + off);
        float q0 = __uint_as_float(uq << 16);
        float q1 = __uint_as_float(uq & 0xffff0000u);
        *(unsigned int*)(Qb + off) = (unsigned int)f2bf(q0 * c - q1 * s) |
                                     ((unsigned int)f2bf(q1 * c + q0 * s) << 16);

        unsigned int uk = *(unsigned int*)(Kb + off);
        float k0 = __uint_as_float(uk << 16);
        float k1 = __uint_as_float(uk & 0xffff0000u);
        *(unsigned int*)(Kb + off) = (unsigned int)f2bf(k0 * c - k1 * s) |
                                     ((unsigned int)f2bf(k1 * c + k0 * s) << 16);
    }
}

// ---------------------------------------------------------------------------
// Flash attention, bf16 MFMA 16x16x32; epilogue emits O as bf16 hi/lo.
// ---------------------------------------------------------------------------
#define PADV 72
__global__ __launch_bounds__(256) void attn_mfma(const unsigned short* __restrict__ Qb,
                                                 const unsigned short* __restrict__ Kb,
                                                 const unsigned short* __restrict__ Vb,
                                                 unsigned short* __restrict__ Ohi,
                                                 unsigned short* __restrict__ Olo) {
    __shared__ __align__(16) unsigned short Vt[64][PADV];
    __shared__ __align__(16) unsigned short Pl[4][16][PADV];
    const int tid = threadIdx.x;
    const int w = tid >> 6;
    const int l = tid & 63;
    const int lr = l & 15, lg = l >> 4;
    const int bh = blockIdx.y;
    const int q0 = blockIdx.x * 64;
    const size_t base = (size_t)bh * N_ * D_;

    const unsigned short* qrow = Qb + base + (size_t)(q0 + w * 16 + lr) * D_ + lg * 8;
    short8 qf0 = *(const short8*)qrow;
    short8 qf1 = *(const short8*)(qrow + 32);

    f32x4 oacc[4] = {};
    float m[4], lsum[4];
#pragma unroll
    for (int r = 0; r < 4; ++r) { m[r] = -1e30f; lsum[r] = 0.f; }

    for (int k0 = 0; k0 < N_; k0 += 64) {
        __syncthreads();
        {
            int kv = tid & 63, d0 = (tid >> 6) * 16;
            const unsigned short* src = Vb + base + (size_t)(k0 + kv) * D_ + d0;
            short8 v0 = *(const short8*)src;
            short8 v1 = *(const short8*)(src + 8);
#pragma unroll
            for (int j = 0; j < 8; ++j) {
                Vt[d0 + j][kv]     = (unsigned short)v0[j];
                Vt[d0 + 8 + j][kv] = (unsigned short)v1[j];
            }
        }
        f32x4 sacc[4] = {};
#pragma unroll
        for (int t = 0; t < 4; ++t) {
            const unsigned short* krow = Kb + base + (size_t)(k0 + t * 16 + lr) * D_ + lg * 8;
            short8 kf0 = *(const short8*)krow;
            short8 kf1 = *(const short8*)(krow + 32);
            sacc[t] = __builtin_amdgcn_mfma_f32_16x16x32_bf16(qf0, kf0, sacc[t], 0, 0, 0);
            sacc[t] = __builtin_amdgcn_mfma_f32_16x16x32_bf16(qf1, kf1, sacc[t], 0, 0, 0);
        }
        __syncthreads();

        float tm[4];
#pragma unroll
        for (int r = 0; r < 4; ++r) tm[r] = -1e30f;
#pragma unroll
        for (int t = 0; t < 4; ++t)
#pragma unroll
            for (int r = 0; r < 4; ++r) {
                float s = sacc[t][r] * 0.125f;
                sacc[t][r] = s;
                tm[r] = fmaxf(tm[r], s);
            }
#pragma unroll
        for (int mask = 1; mask <= 8; mask <<= 1)
#pragma unroll
            for (int r = 0; r < 4; ++r) tm[r] = fmaxf(tm[r], __shfl_xor(tm[r], mask));

        float al[4], ps[4];
#pragma unroll
        for (int r = 0; r < 4; ++r) {
            float nm = fmaxf(m[r], tm[r]);
            al[r] = __expf(m[r] - nm);
            m[r] = nm;
            ps[r] = 0.f;
        }
#pragma unroll
        for (int t = 0; t < 4; ++t)
#pragma unroll
            for (int r = 0; r < 4; ++r) {
                float e = __expf(sacc[t][r] - m[r]);
                ps[r] += e;
                Pl[w][lg * 4 + r][lr + 16 * t] = f2bf(e);
            }
#pragma unroll
        for (int mask = 1; mask <= 8; mask <<= 1)
#pragma unroll
            for (int r = 0; r < 4; ++r) ps[r] += __shfl_xor(ps[r], mask);
#pragma unroll
        for (int r = 0; r < 4; ++r) lsum[r] = lsum[r] * al[r] + ps[r];
#pragma unroll
        for (int dt = 0; dt < 4; ++dt)
#pragma unroll
            for (int r = 0; r < 4; ++r) oacc[dt][r] *= al[r];

#pragma unroll
        for (int hh = 0; hh < 2; ++hh) {
            short8 pf = *(const short8*)&Pl[w][lr][lg * 8 + 32 * hh];
#pragma unroll
            for (int dt = 0; dt < 4; ++dt) {
                short8 vf = *(const short8*)&Vt[dt * 16 + lr][lg * 8 + 32 * hh];
                oacc[dt] = __builtin_amdgcn_mfma_f32_16x16x32_bf16(pf, vf, oacc[dt], 0, 0, 0);
            }
        }
    }

    int b = bh >> 4, h = bh & 15;
#pragma unroll
    for (int r = 0; r < 4; ++r) {
        float inv = 1.0f / lsum[r];
        size_t orow = ((size_t)b * N_ + q0 + w * 16 + lg * 4 + r) * INNER_ + h * 64 + lr;
#pragma unroll
        for (int dt = 0; dt < 4; ++dt) {
            float o = oacc[dt][r] * inv;
            unsigned short hi = f2bf(o);
            Ohi[orow + 16 * dt] = hi;
            Olo[orow + 16 * dt] = f2bf(o - bf2f(hi));
        }
    }
}

// ---------------------------------------------------------------------------
extern "C" void kernel_launch(void* const* d_in, const int* in_sizes, int n_in,
                              void* d_out, int out_size, void* d_ws, size_t ws_size,
                              hipStream_t stream) {
    const float* x     = (const float*)d_in[0];
    const float* w_qkv = (const float*)d_in[1];
    const float* w_out = (const float*)d_in[2];
    const float* b_out = (const float*)d_in[3];
    float* out = (float*)d_out;

    unsigned short* Xhi    = (unsigned short*)d_ws;          // 4M  (reused as Ohi)
    unsigned short* Xlo    = Xhi + 4194304;                  // 4M  (reused as Olo)
    unsigned short* WqT_hi = Xlo + 4194304;                  // 3M
    unsigned short* WqT_lo = WqT_hi + 3145728;               // 3M
    unsigned short* WoT_hi = WqT_lo + 3145728;               // 1M
    unsigned short* WoT_lo = WoT_hi + 1048576;               // 1M
    unsigned short* Qb     = WoT_lo + 1048576;               // 4M
    unsigned short* Kb     = Qb + 4194304;                   // 4M
    unsigned short* Vb     = Kb + 4194304;                   // 4M

    convert_x<<<dim3(2048), 256, 0, stream>>>(x, Xhi, Xlo);
    convert_w_T<<<dim3(QKVC_ / 64, 16), 256, 0, stream>>>(w_qkv, WqT_hi, WqT_lo, QKVC_);
    convert_w_T<<<dim3(DIM_ / 64, 16), 256, 0, stream>>>(w_out, WoT_hi, WoT_lo, DIM_);

    qkv_gemm_mfma<<<dim3(QKVC_ / 128, 32), 256, 0, stream>>>(Xhi, Xlo, WqT_hi, WqT_lo, Qb, Kb, Vb);
    rope_kernel<<<dim3(2048), 256, 0, stream>>>(Qb, Kb);
    attn_mfma<<<dim3(N_ / 64, B_ * H_), 256, 0, stream>>>(Qb, Kb, Vb, Xhi, Xlo);
    out_gemm_mfma<<<dim3(DIM_ / 128, 32), 256, 0, stream>>>(Xhi, Xlo, WoT_hi, WoT_lo, b_out, out);
}

// Round 4
// 316.427 us; speedup vs baseline: 11.6544x; 1.0777x over previous
//
#include <hip/hip_runtime.h>
#include <math.h>

#define B_    2
#define N_    2048
#define DIM_  1024
#define H_    16
#define D_    64
#define INNER_ 1024
#define QKVC_ 3072

typedef __attribute__((ext_vector_type(8))) short short8;
typedef __attribute__((ext_vector_type(4))) short short4v;
typedef __attribute__((ext_vector_type(4))) float f32x4;
typedef __attribute__((ext_vector_type(4))) float float4v;

static __device__ __forceinline__ unsigned short f2bf(float f) {
    unsigned int u = __float_as_uint(f);
    u = (u + 0x7fff + ((u >> 16) & 1)) >> 16;   // RNE
    return (unsigned short)u;
}
static __device__ __forceinline__ float bf2f(unsigned short b) {
    return __uint_as_float(((unsigned int)b) << 16);
}

static __device__ __forceinline__ void gload16(const void* g, void* l) {
    __builtin_amdgcn_global_load_lds((__attribute__((address_space(1))) void*)(g),
                                     (__attribute__((address_space(3))) void*)(l),
                                     16, 0, 0);
}

// ---------------------------------------------------------------------------
// convert_x: fp32 (rows x 1024) -> bf16 hi/lo, same layout. 8 elems/thread.
// ---------------------------------------------------------------------------
__global__ __launch_bounds__(256) void convert_x(const float* __restrict__ X,
                                                 unsigned short* __restrict__ Xhi,
                                                 unsigned short* __restrict__ Xlo) {
    int t = blockIdx.x * blockDim.x + threadIdx.x;
    size_t off = (size_t)t * 8;
    float4v a = *(const float4v*)(X + off);
    float4v b = *(const float4v*)(X + off + 4);
    short8 hi, lo;
#pragma unroll
    for (int j = 0; j < 4; ++j) {
        unsigned short h = f2bf(a[j]); hi[j] = (short)h; lo[j] = (short)f2bf(a[j] - bf2f(h));
        unsigned short h2 = f2bf(b[j]); hi[4 + j] = (short)h2; lo[4 + j] = (short)f2bf(b[j] - bf2f(h2));
    }
    *(short8*)(Xhi + off) = hi;
    *(short8*)(Xlo + off) = lo;
}

// ---------------------------------------------------------------------------
// convert_w_T: W fp32 (K=1024 x Nw) -> W^T bf16 hi/lo (Nw x 1024).
// ---------------------------------------------------------------------------
__global__ __launch_bounds__(256) void convert_w_T(const float* __restrict__ W,
                                                   unsigned short* __restrict__ Thi,
                                                   unsigned short* __restrict__ Tlo,
                                                   int Nw) {
    __shared__ unsigned short Shi[64][65];
    __shared__ unsigned short Slo[64][65];
    const int tid = threadIdx.x;
    const int n0 = blockIdx.x * 64;
    const int k0 = blockIdx.y * 64;
#pragma unroll
    for (int l = 0; l < 16; ++l) {
        int idx = tid + l * 256;
        int r = idx >> 6, c = idx & 63;
        float v = W[(size_t)(k0 + r) * Nw + n0 + c];
        unsigned short h = f2bf(v);
        Shi[c][r] = h;
        Slo[c][r] = f2bf(v - bf2f(h));
    }
    __syncthreads();
#pragma unroll
    for (int l = 0; l < 16; ++l) {
        int idx = tid + l * 256;
        int r = idx >> 6, c = idx & 63;
        size_t o = (size_t)(n0 + r) * 1024 + k0 + c;
        Thi[o] = Shi[r][c];
        Tlo[o] = Slo[r][c];
    }
}

// ---------------------------------------------------------------------------
// Split-bf16 GEMM core: C(M x N) = A(M x 1024) * B^T(N x 1024), fp32 acc.
// ---------------------------------------------------------------------------
#define GEMM_STAGE(gA_hi, gA_lo, gB_hi, gB_lo)                                     \
    {                                                                              \
        int c0 = w * 2, c1 = w * 2 + 1;                                            \
        int ra0 = c0 * 16 + (lane >> 2), ra1 = c1 * 16 + (lane >> 2);              \
        int kc = (lane & 3) * 8;                                                   \
        gload16(gA_hi + (size_t)(m0 + ra0) * 1024 + k0 + kc, sAhi + c0 * 512);     \
        gload16(gA_hi + (size_t)(m0 + ra1) * 1024 + k0 + kc, sAhi + c1 * 512);     \
        gload16(gA_lo + (size_t)(m0 + ra0) * 1024 + k0 + kc, sAlo + c0 * 512);     \
        gload16(gA_lo + (size_t)(m0 + ra1) * 1024 + k0 + kc, sAlo + c1 * 512);     \
        gload16(gB_hi + (size_t)(n0 + ra0) * 1024 + k0 + kc, sBhi + c0 * 512);     \
        gload16(gB_hi + (size_t)(n0 + ra1) * 1024 + k0 + kc, sBhi + c1 * 512);     \
        gload16(gB_lo + (size_t)(n0 + ra0) * 1024 + k0 + kc, sBlo + c0 * 512);     \
        gload16(gB_lo + (size_t)(n0 + ra1) * 1024 + k0 + kc, sBlo + c1 * 512);     \
    }

#define GEMM_BODY()                                                                \
    short8 ah[4], al[4], bh[4], bl[4];                                             \
    _Pragma("unroll") for (int f = 0; f < 4; ++f) {                                \
        int offa = (wr + f * 16 + (lane & 15)) * 32 + (lane >> 4) * 8;             \
        ah[f] = *(const short8*)&sAhi[offa];                                       \
        al[f] = *(const short8*)&sAlo[offa];                                       \
        int offb = (wc + f * 16 + (lane & 15)) * 32 + (lane >> 4) * 8;             \
        bh[f] = *(const short8*)&sBhi[offb];                                       \
        bl[f] = *(const short8*)&sBlo[offb];                                       \
    }                                                                              \
    _Pragma("unroll") for (int i = 0; i < 4; ++i)                                  \
        _Pragma("unroll") for (int j = 0; j < 4; ++j) {                            \
            acc[i][j] = __builtin_amdgcn_mfma_f32_16x16x32_bf16(ah[i], bh[j], acc[i][j], 0, 0, 0); \
            acc[i][j] = __builtin_amdgcn_mfma_f32_16x16x32_bf16(al[i], bh[j], acc[i][j], 0, 0, 0); \
            acc[i][j] = __builtin_amdgcn_mfma_f32_16x16x32_bf16(ah[i], bl[j], acc[i][j], 0, 0, 0); \
        }

__global__ __launch_bounds__(256) void qkv_gemm_mfma(const unsigned short* __restrict__ Ahi,
                                                     const unsigned short* __restrict__ Alo,
                                                     const unsigned short* __restrict__ Bhi,
                                                     const unsigned short* __restrict__ Blo,
                                                     unsigned short* __restrict__ Qb,
                                                     unsigned short* __restrict__ Kb,
                                                     unsigned short* __restrict__ Vb) {
    __shared__ __align__(16) unsigned short sAhi[4096], sAlo[4096], sBhi[4096], sBlo[4096];
    const int tid = threadIdx.x;
    const int lane = tid & 63, w = tid >> 6;
    const int wr = (w >> 1) * 64, wc = (w & 1) * 64;
    const int m0 = blockIdx.y * 128, n0 = blockIdx.x * 128;
    f32x4 acc[4][4] = {};

    for (int k0 = 0; k0 < 1024; k0 += 32) {
        GEMM_STAGE(Ahi, Alo, Bhi, Blo);
        __syncthreads();
        GEMM_BODY();
        __syncthreads();
    }

#pragma unroll
    for (int i = 0; i < 4; ++i) {
        int mbase = m0 + wr + i * 16 + (lane >> 4) * 4;
#pragma unroll
        for (int j = 0; j < 4; ++j) {
            int col = n0 + wc + j * 16 + (lane & 15);
            int seg = col >> 10;
            int wcol = col & 1023;
            int h = wcol >> 6, dd = wcol & 63;
            unsigned short* dst = (seg == 0) ? Qb : (seg == 1 ? Kb : Vb);
#pragma unroll
            for (int r = 0; r < 4; ++r) {
                int row = mbase + r;
                int b = row >> 11, n = row & (N_ - 1);
                dst[((size_t)(b * H_ + h) * N_ + n) * D_ + dd] = f2bf(acc[i][j][r]);
            }
        }
    }
}

__global__ __launch_bounds__(256) void out_gemm_mfma(const unsigned short* __restrict__ Ahi,
                                                     const unsigned short* __restrict__ Alo,
                                                     const unsigned short* __restrict__ Bhi,
                                                     const unsigned short* __restrict__ Blo,
                                                     const float* __restrict__ bias,
                                                     float* __restrict__ C) {
    __shared__ __align__(16) unsigned short sAhi[4096], sAlo[4096], sBhi[4096], sBlo[4096];
    const int tid = threadIdx.x;
    const int lane = tid & 63, w = tid >> 6;
    const int wr = (w >> 1) * 64, wc = (w & 1) * 64;
    const int m0 = blockIdx.y * 128, n0 = blockIdx.x * 128;
    f32x4 acc[4][4] = {};

    for (int k0 = 0; k0 < 1024; k0 += 32) {
        GEMM_STAGE(Ahi, Alo, Bhi, Blo);
        __syncthreads();
        GEMM_BODY();
        __syncthreads();
    }

#pragma unroll
    for (int i = 0; i < 4; ++i) {
        int mbase = m0 + wr + i * 16 + (lane >> 4) * 4;
#pragma unroll
        for (int j = 0; j < 4; ++j) {
            int col = n0 + wc + j * 16 + (lane & 15);
            float bv = bias[col];
#pragma unroll
            for (int r = 0; r < 4; ++r)
                C[(size_t)(mbase + r) * DIM_ + col] = acc[i][j][r] + bv;
        }
    }
}

// ---------------------------------------------------------------------------
// RoPE in-place on bf16 Q and K
// ---------------------------------------------------------------------------
__global__ void rope_kernel(unsigned short* __restrict__ Qb,
                            unsigned short* __restrict__ Kb) {
    const int total = B_ * H_ * N_ * (D_ / 2);
    for (int p = blockIdx.x * blockDim.x + threadIdx.x; p < total;
         p += gridDim.x * blockDim.x) {
        int d2 = p & 31;
        int rest = p >> 5;
        int n = rest & (N_ - 1);
        size_t off = (size_t)rest * D_ + 2 * d2;
        float freq = powf(10000.0f, -(float)d2 * (1.0f / 32.0f));
        float ang = (float)n * freq;
        float s, c;
        sincosf(ang, &s, &c);

        unsigned int uq = *(unsigned int*)(Qb + off);
        float q0 = __uint_as_float(uq << 16);
        float q1 = __uint_as_float(uq & 0xffff0000u);
        *(unsigned int*)(Qb + off) = (unsigned int)f2bf(q0 * c - q1 * s) |
                                     ((unsigned int)f2bf(q1 * c + q0 * s) << 16);

        unsigned int uk = *(unsigned int*)(Kb + off);
        float k0 = __uint_as_float(uk << 16);
        float k1 = __uint_as_float(uk & 0xffff0000u);
        *(unsigned int*)(Kb + off) = (unsigned int)f2bf(k0 * c - k1 * s) |
                                     ((unsigned int)f2bf(k1 * c + k0 * s) << 16);
    }
}

// ---------------------------------------------------------------------------
// Flash attention v2: swapped QK^T (S^T = K·Q^T), in-register P, V dbuf LDS.
// Block = 512 threads (8 waves) x 128 q-rows; wave w owns q0+w*16..+15.
// S^T C-layout: lane q=l&15, kv=(l>>4)*4+reg (+16t)  -> softmax in-register.
// PV k-map: kappa=lg*8+j -> kv = 16*(2m+(j>>2)) + 4*lg + (j&3): A-frag slots
// are the lane's own p-values; B-frag = 2x ds_read_b64 from Vt[d][kv].
// PV C-layout: lane d=l&15, q=(l>>4)*4+reg (matches R1-verified epilogue).
// ---------------------------------------------------------------------------
#define PADV 68
__global__ __launch_bounds__(512) void attn_mfma(const unsigned short* __restrict__ Qb,
                                                 const unsigned short* __restrict__ Kb,
                                                 const unsigned short* __restrict__ Vb,
                                                 unsigned short* __restrict__ Ohi,
                                                 unsigned short* __restrict__ Olo) {
    __shared__ __align__(16) unsigned short Vt[2][64][PADV];   // V^T: [d][kv]
    const int tid = threadIdx.x;
    const int w = tid >> 6;
    const int l = tid & 63;
    const int lr = l & 15, lg = l >> 4;
    const int bh = blockIdx.y;
    const int q0 = blockIdx.x * 128;
    const size_t base = (size_t)bh * N_ * D_;

    // Q as B-operand: lane holds col q=lr, k d=lg*8+j (+32h)
    const unsigned short* qrow = Qb + base + (size_t)(q0 + w * 16 + lr) * D_ + lg * 8;
    const short8 qf0 = *(const short8*)qrow;
    const short8 qf1 = *(const short8*)(qrow + 32);

    // V staging coords (512 threads): d0=(tid&15)*4, kv0=(tid>>4)*2
    const int sd0 = (tid & 15) * 4;
    const int skv = (tid >> 4) * 2;

    f32x4 oacc[4] = {};           // [dt]: q=lg*4+r, d=dt*16+lr
    float mrow = -1e30f, lsum = 0.f;   // per-lane state for q-row lr (dup x4)

    // prologue: stage tile 0
    {
        short4v r0 = *(const short4v*)(Vb + base + (size_t)(skv + 0) * D_ + sd0);
        short4v r1 = *(const short4v*)(Vb + base + (size_t)(skv + 1) * D_ + sd0);
#pragma unroll
        for (int j = 0; j < 4; ++j) {
            unsigned int pk = (unsigned int)(unsigned short)r0[j] |
                              ((unsigned int)(unsigned short)r1[j] << 16);
            *(unsigned int*)&Vt[0][sd0 + j][skv] = pk;
        }
    }

    for (int ti = 0; ti < N_ / 64; ++ti) {
        const int cur = ti & 1;
        __syncthreads();

        // T14: issue next V tile loads early
        short4v n0v, n1v;
        if (ti + 1 < N_ / 64) {
            const unsigned short* nsrc = Vb + base + (size_t)((ti + 1) * 64 + skv) * D_ + sd0;
            n0v = *(const short4v*)nsrc;
            n1v = *(const short4v*)(nsrc + D_);
        }

        // ---- S^T = K·Q^T : A=K rows, B=Q rows ----
        f32x4 sacc[4] = {};
        __builtin_amdgcn_s_setprio(1);
#pragma unroll
        for (int t = 0; t < 4; ++t) {
            const unsigned short* krow = Kb + base + (size_t)(ti * 64 + t * 16 + lr) * D_ + lg * 8;
            short8 kf0 = *(const short8*)krow;
            short8 kf1 = *(const short8*)(krow + 32);
            sacc[t] = __builtin_amdgcn_mfma_f32_16x16x32_bf16(kf0, qf0, sacc[t], 0, 0, 0);
            sacc[t] = __builtin_amdgcn_mfma_f32_16x16x32_bf16(kf1, qf1, sacc[t], 0, 0, 0);
        }
        __builtin_amdgcn_s_setprio(0);

        // ---- softmax: lane owns 16 kv of q-row lr ----
        float tm = -1e30f;
#pragma unroll
        for (int t = 0; t < 4; ++t)
#pragma unroll
            for (int r = 0; r < 4; ++r) {
                float s = sacc[t][r] * 0.125f;
                sacc[t][r] = s;
                tm = fmaxf(tm, s);
            }
        tm = fmaxf(tm, __shfl_xor(tm, 16));
        tm = fmaxf(tm, __shfl_xor(tm, 32));
        float nm = fmaxf(mrow, tm);
        float al = __expf(mrow - nm);
        mrow = nm;

        float p[4][4];
        float ps = 0.f;
#pragma unroll
        for (int t = 0; t < 4; ++t)
#pragma unroll
            for (int r = 0; r < 4; ++r) {
                float e = __expf(sacc[t][r] - nm);
                p[t][r] = e;
                ps += e;
            }
        ps += __shfl_xor(ps, 16);
        ps += __shfl_xor(ps, 32);
        lsum = lsum * al + ps;

        // O rescale: alpha for q=lg*4+r comes from lane lg*4+r
#pragma unroll
        for (int r = 0; r < 4; ++r) {
            float alq = __shfl(al, lg * 4 + r);
#pragma unroll
            for (int dt = 0; dt < 4; ++dt) oacc[dt][r] *= alq;
        }

        // pack A-frags: pa[m] = {p[2m][0..3], p[2m+1][0..3]} as bf16
        short8 pa[2];
#pragma unroll
        for (int m2 = 0; m2 < 2; ++m2)
#pragma unroll
            for (int r = 0; r < 4; ++r) {
                pa[m2][r]     = (short)f2bf(p[2 * m2][r]);
                pa[m2][4 + r] = (short)f2bf(p[2 * m2 + 1][r]);
            }

        // ---- PV ----
        __builtin_amdgcn_s_setprio(1);
#pragma unroll
        for (int m2 = 0; m2 < 2; ++m2)
#pragma unroll
            for (int dt = 0; dt < 4; ++dt) {
                short4v v0 = *(const short4v*)&Vt[cur][dt * 16 + lr][m2 * 32 + lg * 4];
                short4v v1 = *(const short4v*)&Vt[cur][dt * 16 + lr][m2 * 32 + 16 + lg * 4];
                short8 vb = {v0[0], v0[1], v0[2], v0[3], v1[0], v1[1], v1[2], v1[3]};
                oacc[dt] = __builtin_amdgcn_mfma_f32_16x16x32_bf16(pa[m2], vb, oacc[dt], 0, 0, 0);
            }
        __builtin_amdgcn_s_setprio(0);

        // T14 write-late: commit next V tile into other buffer
        if (ti + 1 < N_ / 64) {
#pragma unroll
            for (int j = 0; j < 4; ++j) {
                unsigned int pk = (unsigned int)(unsigned short)n0v[j] |
                                  ((unsigned int)(unsigned short)n1v[j] << 16);
                *(unsigned int*)&Vt[cur ^ 1][sd0 + j][skv] = pk;
            }
        }
    }

    // ---- epilogue ----
    int b = bh >> 4, h = bh & 15;
#pragma unroll
    for (int r = 0; r < 4; ++r) {
        float ls = __shfl(lsum, lg * 4 + r);
        float inv = 1.0f / ls;
        size_t orow = ((size_t)b * N_ + q0 + w * 16 + lg * 4 + r) * INNER_ + h * 64 + lr;
#pragma unroll
        for (int dt = 0; dt < 4; ++dt) {
            float o = oacc[dt][r] * inv;
            unsigned short hi = f2bf(o);
            Ohi[orow + 16 * dt] = hi;
            Olo[orow + 16 * dt] = f2bf(o - bf2f(hi));
        }
    }
}

// ---------------------------------------------------------------------------
extern "C" void kernel_launch(void* const* d_in, const int* in_sizes, int n_in,
                              void* d_out, int out_size, void* d_ws, size_t ws_size,
                              hipStream_t stream) {
    const float* x     = (const float*)d_in[0];
    const float* w_qkv = (const float*)d_in[1];
    const float* w_out = (const float*)d_in[2];
    const float* b_out = (const float*)d_in[3];
    float* out = (float*)d_out;

    unsigned short* Xhi    = (unsigned short*)d_ws;          // 4M  (reused as Ohi)
    unsigned short* Xlo    = Xhi + 4194304;                  // 4M  (reused as Olo)
    unsigned short* WqT_hi = Xlo + 4194304;                  // 3M
    unsigned short* WqT_lo = WqT_hi + 3145728;               // 3M
    unsigned short* WoT_hi = WqT_lo + 3145728;               // 1M
    unsigned short* WoT_lo = WoT_hi + 1048576;               // 1M
    unsigned short* Qb     = WoT_lo + 1048576;               // 4M
    unsigned short* Kb     = Qb + 4194304;                   // 4M
    unsigned short* Vb     = Kb + 4194304;                   // 4M

    convert_x<<<dim3(2048), 256, 0, stream>>>(x, Xhi, Xlo);
    convert_w_T<<<dim3(QKVC_ / 64, 16), 256, 0, stream>>>(w_qkv, WqT_hi, WqT_lo, QKVC_);
    convert_w_T<<<dim3(DIM_ / 64, 16), 256, 0, stream>>>(w_out, WoT_hi, WoT_lo, DIM_);

    qkv_gemm_mfma<<<dim3(QKVC_ / 128, 32), 256, 0, stream>>>(Xhi, Xlo, WqT_hi, WqT_lo, Qb, Kb, Vb);
    rope_kernel<<<dim3(2048), 256, 0, stream>>>(Qb, Kb);
    attn_mfma<<<dim3(N_ / 128, B_ * H_), 512, 0, stream>>>(Qb, Kb, Vb, Xhi, Xlo);
    out_gemm_mfma<<<dim3(DIM_ / 128, 32), 256, 0, stream>>>(Xhi, Xlo, WoT_hi, WoT_lo, b_out, out);
}